// Round 1
// baseline (2177.010 us; speedup 1.0000x reference)
//
#include <hip/hip_runtime.h>
#include <cmath>

#define D_MODEL 1024
#define QLEN    1024
#define NHEAD   16
#define DHEAD   64
#define BSZ     4

// ---------------------------------------------------------------------------
// Tiled fp32 GEMM: C[b][m][n] = sum_k W[m][k] * X[b][k][n] + epilogue
//   MODE 0: + U[b][m][n]            (QKV projection, U = u)
//   MODE 1: (nothing)               (r_head_k)
//   MODE 2: + bias[m] + res[b][m][n] (output projection + o_b + residual z)
// Block: 256 threads, 128x128 tile, BK=16, 8x8 micro-tile per thread.
// ---------------------------------------------------------------------------
template<int MODE>
__global__ __launch_bounds__(256)
void gemm_kernel(const float* __restrict__ W, const float* __restrict__ X,
                 const float* __restrict__ U, const float* __restrict__ bias,
                 const float* __restrict__ res, float* __restrict__ C,
                 int M, int K, int N)
{
    const int b  = blockIdx.z;
    const int m0 = blockIdx.y * 128;
    const int n0 = blockIdx.x * 128;
    const float* Xb = X + (size_t)b * K * N;

    __shared__ __align__(16) float Ws[16][132];  // [k][m]
    __shared__ __align__(16) float Xs[16][132];  // [k][n]

    const int t  = threadIdx.x;
    const int tx = t & 15, ty = t >> 4;

    float acc[8][8];
#pragma unroll
    for (int i = 0; i < 8; ++i)
#pragma unroll
        for (int j = 0; j < 8; ++j) acc[i][j] = 0.f;

    for (int k0 = 0; k0 < K; k0 += 16) {
        // stage W tile (128 x 16), transposed into Ws[k][m]
        {
            const int r  = t >> 2;
            const int c4 = (t & 3) * 4;
#pragma unroll
            for (int rr = 0; rr < 2; ++rr) {
                const int m = r + rr * 64;
                const float4 w4 = *(const float4*)(W + (size_t)(m0 + m) * K + k0 + c4);
                Ws[c4 + 0][m] = w4.x;
                Ws[c4 + 1][m] = w4.y;
                Ws[c4 + 2][m] = w4.z;
                Ws[c4 + 3][m] = w4.w;
            }
        }
        // stage X tile (16 x 128)
        {
            const int kk = t >> 4;
            const int n4 = (t & 15) * 4;
#pragma unroll
            for (int cc = 0; cc < 2; ++cc) {
                const int n = n4 + cc * 64;
                *(float4*)&Xs[kk][n] = *(const float4*)(Xb + (size_t)(k0 + kk) * N + n0 + n);
            }
        }
        __syncthreads();

#pragma unroll
        for (int k = 0; k < 16; ++k) {
            float a[8], bb[8];
            *(float4*)&a[0]  = *(const float4*)&Ws[k][ty * 4];
            *(float4*)&a[4]  = *(const float4*)&Ws[k][64 + ty * 4];
            *(float4*)&bb[0] = *(const float4*)&Xs[k][tx * 4];
            *(float4*)&bb[4] = *(const float4*)&Xs[k][64 + tx * 4];
#pragma unroll
            for (int i = 0; i < 8; ++i)
#pragma unroll
                for (int j = 0; j < 8; ++j)
                    acc[i][j] += a[i] * bb[j];
        }
        __syncthreads();
    }

    float* Cb = C + (size_t)b * M * N;
#pragma unroll
    for (int i = 0; i < 8; ++i) {
        const int m = m0 + ((i < 4) ? (ty * 4 + i) : (64 + ty * 4 + (i - 4)));
#pragma unroll
        for (int jj = 0; jj < 2; ++jj) {
            const int n = n0 + jj * 64 + tx * 4;
            float4 v;
            v.x = acc[i][jj * 4 + 0];
            v.y = acc[i][jj * 4 + 1];
            v.z = acc[i][jj * 4 + 2];
            v.w = acc[i][jj * 4 + 3];
            const size_t off = (size_t)m * N + n;
            if (MODE == 0) {
                const float4 u4 = *(const float4*)(U + (size_t)b * M * N + off);
                v.x += u4.x; v.y += u4.y; v.z += u4.z; v.w += u4.w;
            } else if (MODE == 2) {
                const float bm = bias[m];
                const float4 r4 = *(const float4*)(res + (size_t)b * M * N + off);
                v.x += bm + r4.x; v.y += bm + r4.y; v.z += bm + r4.z; v.w += bm + r4.w;
            }
            *(float4*)(Cb + off) = v;
        }
    }
}

// ---------------------------------------------------------------------------
// Fused rel-attention, fp32, flash-style online softmax.
// Grid: (qlen/64, n_head, bsz). Block: 256 threads, i-tile = 64 rows.
// score(i,j) = [ sum_d q[d,i]*(k[d,j] + rk[d, r(i,j)]) + kb[j] + rb[r] ] / 8
//   with r(i,j) = 1023 - (i - j)   (Transformer-XL rel_shift on causal region)
// mask: j <= i  and  j >= i - 999
// ---------------------------------------------------------------------------
__global__ __launch_bounds__(256)
void attn_kernel(const float* __restrict__ wh,   // (B, 3072, 1024): q|k|v rows n*64+d
                 const float* __restrict__ rk,   // (1024, 1024): row n*64+d
                 const float* __restrict__ rwb,  // (16,64)
                 const float* __restrict__ rrb,  // (16,64)
                 float* __restrict__ av)         // (B, 1024, 1024)
{
    const int i0 = blockIdx.x * 64;
    const int n  = blockIdx.y;
    const int b  = blockIdx.z;

    const float* qg  = wh + ((size_t)b * 3072 + n * 64) * 1024;
    const float* kg  = qg + (size_t)1024 * 1024;
    const float* vg  = qg + (size_t)2048 * 1024;
    const float* rkg = rk + (size_t)(n * 64) * 1024;

    __shared__ __align__(16) float qs[64][65];    // [d][i]
    __shared__ __align__(16) float ks[64][68];    // [d][j]  (stride 68 -> aligned float4 rows)
    __shared__ __align__(16) float vt[64][65];    // [j][d]  (broadcast reads in PV)
    __shared__ __align__(16) float rks[64][136];  // [d][rr], rr in [0,128)
    __shared__ __align__(16) float sc[64][66];    // [i][j] probs
    __shared__ float kb[64], rb[128];
    __shared__ float rwbs[64], rrbs[64];
    __shared__ float mrow[64], lrow[64], crow[64];

    const int t = threadIdx.x;

    // Q tile
    for (int idx = t; idx < 64 * 64; idx += 256) {
        const int d = idx >> 6, ii = idx & 63;
        qs[d][ii] = qg[(size_t)d * 1024 + i0 + ii];
    }
    if (t < 64) {
        rwbs[t] = rwb[n * 64 + t];
        rrbs[t] = rrb[n * 64 + t];
        mrow[t] = -INFINITY;
        lrow[t] = 0.f;
    }

    float acc[16];
#pragma unroll
    for (int i = 0; i < 16; ++i) acc[i] = 0.f;

    const int ai = t & 63;   // PV/epilogue: owned row i
    const int dg = t >> 6;   // PV/epilogue: d block (16 d's)
    const int si = t >> 2;   // score phase: row i
    const int g  = t & 3;    // score phase: j-quarter

    const int njt = i0 / 64 + 1;
    for (int jt = 0; jt < njt; ++jt) {
        const int j0 = jt * 64;
        __syncthreads();  // protect ks/vt/rks/sc from previous iteration's readers

        for (int idx = t; idx < 64 * 64; idx += 256) {
            const int d = idx >> 6, jj = idx & 63;
            const float kv = kg[(size_t)d * 1024 + j0 + jj];
            const float vv = vg[(size_t)d * 1024 + j0 + jj];
            ks[d][jj] = kv;
            vt[jj][d] = vv;
        }
        const int rbase = j0 - i0 + 960;
        for (int idx = t; idx < 64 * 128; idx += 256) {
            const int d = idx >> 7, rr = idx & 127;
            const int r = rbase + rr;
            rks[d][rr] = (r >= 0 && r < 1024) ? rkg[(size_t)d * 1024 + r] : 0.f;
        }
        __syncthreads();

        // per-tile bias rows: kb[j] = sum_d rwb[d]*k[d][j]; rb[rr] = sum_d rrb[d]*rk[d][rr]
        if (t < 64) {
            float s = 0.f;
            for (int d = 0; d < 64; ++d) s += rwbs[d] * ks[d][t];
            kb[t] = s;
        } else if (t < 192) {
            const int rr = t - 64;
            float s = 0.f;
            for (int d = 0; d < 64; ++d) s += rrbs[d] * rks[d][rr];
            rb[rr] = s;
        }
        __syncthreads();

        // scores: thread owns (i=si, j = g*16 .. g*16+15); rr_local = 63 - si + j_local
        float p[16];
#pragma unroll
        for (int jj = 0; jj < 16; ++jj) p[jj] = 0.f;
        const int rro = 63 - si + g * 16;
        for (int d = 0; d < 64; ++d) {
            const float qv = qs[d][si];
            float4 k4[4];
#pragma unroll
            for (int q4 = 0; q4 < 4; ++q4)
                k4[q4] = *(const float4*)&ks[d][g * 16 + q4 * 4];
            const float* kf = (const float*)k4;
#pragma unroll
            for (int jj = 0; jj < 16; ++jj)
                p[jj] += qv * (kf[jj] + rks[d][rro + jj]);
        }

        float tmax = -INFINITY;
#pragma unroll
        for (int jj = 0; jj < 16; ++jj) {
            const int sj = g * 16 + jj;
            float s = (p[jj] + kb[sj] + rb[63 - si + sj]) * 0.125f;
            const int gi = i0 + si, gj = j0 + sj;
            const bool valid = (gj <= gi) && (gj >= gi - 999);
            s = valid ? s : -INFINITY;
            p[jj] = s;
            tmax = fmaxf(tmax, s);
        }
        tmax = fmaxf(tmax, __shfl_xor(tmax, 1, 4));
        tmax = fmaxf(tmax, __shfl_xor(tmax, 2, 4));

        const float mold = mrow[si];
        const float mnew = fmaxf(mold, tmax);
        float tsum = 0.f;
#pragma unroll
        for (int jj = 0; jj < 16; ++jj) {
            const float e = __expf(p[jj] - mnew);   // exp(-inf - finite) = 0
            sc[si][g * 16 + jj] = e;
            tsum += e;
        }
        tsum += __shfl_xor(tsum, 1, 4);
        tsum += __shfl_xor(tsum, 2, 4);
        if (g == 0) {
            const float c = __expf(mold - mnew);    // first tile: exp(-inf) = 0
            crow[si] = c;
            mrow[si] = mnew;
            lrow[si] = lrow[si] * c + tsum;
        }
        __syncthreads();

        // PV: thread owns (i=ai, d = dg*16 .. dg*16+15); vt reads are wave-uniform
        const float cf = crow[ai];
#pragma unroll
        for (int dd = 0; dd < 16; ++dd) acc[dd] *= cf;
        for (int j = 0; j < 64; ++j) {
            const float pv = sc[ai][j];
            const float* vrow = &vt[j][dg * 16];
#pragma unroll
            for (int dd = 0; dd < 16; ++dd)
                acc[dd] += pv * vrow[dd];
        }
    }

    __syncthreads();
    const float linv = 1.f / lrow[ai];
#pragma unroll
    for (int dd = 0; dd < 16; ++dd) {
        const int d = dg * 16 + dd;
        av[((size_t)b * 1024 + (n * 64 + d)) * 1024 + i0 + ai] = acc[dd] * linv;
    }
}

// ---------------------------------------------------------------------------
// In-place channel LayerNorm over dim 1 of (B, 1024, 1024).
// Grid: (qlen/64, B). 256 threads: 4 c-chunks x 64 l's.
// ---------------------------------------------------------------------------
__global__ __launch_bounds__(256)
void ln_kernel(float* __restrict__ x)
{
    const int b  = blockIdx.y;
    const int li = threadIdx.x & 63;
    const int cp = threadIdx.x >> 6;
    const int l  = blockIdx.x * 64 + li;
    float* xb = x + (size_t)b * D_MODEL * QLEN;

    float s = 0.f, s2 = 0.f;
    for (int c = cp * 256; c < (cp + 1) * 256; ++c) {
        const float v = xb[(size_t)c * QLEN + l];
        s += v; s2 += v * v;
    }
    __shared__ float sum1[4][64], sum2[4][64], mean[64], rstd[64];
    sum1[cp][li] = s;
    sum2[cp][li] = s2;
    __syncthreads();
    if (threadIdx.x < 64) {
        const int q = threadIdx.x;
        const float a  = sum1[0][q] + sum1[1][q] + sum1[2][q] + sum1[3][q];
        const float a2 = sum2[0][q] + sum2[1][q] + sum2[2][q] + sum2[3][q];
        const float mu  = a * (1.f / 1024.f);
        const float var = a2 * (1.f / 1024.f) - mu * mu;
        mean[q] = mu;
        rstd[q] = rsqrtf(var + 1e-5f);
    }
    __syncthreads();
    const float mu = mean[li];
    const float rs = rstd[li];
    for (int c = cp * 256; c < (cp + 1) * 256; ++c) {
        const size_t idx = (size_t)c * QLEN + l;
        xb[idx] = (xb[idx] - mu) * rs;
    }
}

// ---------------------------------------------------------------------------
extern "C" void kernel_launch(void* const* d_in, const int* in_sizes, int n_in,
                              void* d_out, int out_size, void* d_ws, size_t ws_size,
                              hipStream_t stream)
{
    const float* z     = (const float*)d_in[0];  // (4, 1024, 1024)
    const float* pos   = (const float*)d_in[1];  // (1, 1024, 1024)
    const float* u     = (const float*)d_in[2];  // (4, 3072, 1024)
    const float* qkv_w = (const float*)d_in[3];  // (3072, 1024)
    const float* r_w   = (const float*)d_in[4];  // (1024, 1024)
    const float* rwb   = (const float*)d_in[5];  // (16, 64)
    const float* rrb   = (const float*)d_in[6];  // (16, 64)
    const float* o_w   = (const float*)d_in[7];  // (1024, 1024)
    const float* o_b   = (const float*)d_in[8];  // (1024,)
    float* out = (float*)d_out;                  // (4, 1024, 1024)

    float* wh  = (float*)d_ws;                              // 4*3072*1024
    float* rkw = wh + (size_t)4 * 3072 * 1024;              // 1024*1024
    float* avb = rkw + (size_t)1024 * 1024;                 // 4*1024*1024

    // 1. w_heads = qkv_w @ z + u
    gemm_kernel<0><<<dim3(8, 24, 4), 256, 0, stream>>>(
        qkv_w, z, u, nullptr, nullptr, wh, 3072, 1024, 1024);

    // 2. r_head_k = r_w @ pos_emb
    gemm_kernel<1><<<dim3(8, 8, 1), 256, 0, stream>>>(
        r_w, pos, nullptr, nullptr, nullptr, rkw, 1024, 1024, 1024);

    // 3. fused rel-attention -> attn_vec
    attn_kernel<<<dim3(16, 16, 4), 256, 0, stream>>>(wh, rkw, rwb, rrb, avb);

    // 4. pre = o_w @ attn_vec + o_b + z   (into d_out)
    gemm_kernel<2><<<dim3(8, 8, 4), 256, 0, stream>>>(
        o_w, avb, nullptr, o_b, z, out, 1024, 1024, 1024);

    // 5. channel LayerNorm in place
    ln_kernel<<<dim3(16, 4), 256, 0, stream>>>(out);
}

// Round 2
// 870.641 us; speedup vs baseline: 2.5005x; 2.5005x over previous
//
#include <hip/hip_runtime.h>
#include <cmath>

#define D_MODEL 1024
#define QLEN    1024
#define NHEAD   16
#define DHEAD   64
#define BSZ     4

typedef __bf16 bf16x8 __attribute__((ext_vector_type(8)));
typedef __bf16 bf16x4 __attribute__((ext_vector_type(4)));
typedef float  f32x4  __attribute__((ext_vector_type(4)));

static __device__ __forceinline__ __bf16 f2bf(float x) { return (__bf16)x; }

#define MFMA16(a, b, c) __builtin_amdgcn_mfma_f32_16x16x32_bf16((a), (b), (c), 0, 0, 0)

// ---------------------------------------------------------------------------
// Tiled fp32 GEMM: C[b][m][n] = sum_k W[m][k] * X[b][k][n] + epilogue
//   MODE 0: + U[b][m][n]  | MODE 1: none | MODE 2: + bias[m] + res[b][m][n]
// ---------------------------------------------------------------------------
template<int MODE>
__global__ __launch_bounds__(256)
void gemm_kernel(const float* __restrict__ W, const float* __restrict__ X,
                 const float* __restrict__ U, const float* __restrict__ bias,
                 const float* __restrict__ res, float* __restrict__ C,
                 int M, int K, int N)
{
    const int b  = blockIdx.z;
    const int m0 = blockIdx.y * 128;
    const int n0 = blockIdx.x * 128;
    const float* Xb = X + (size_t)b * K * N;

    __shared__ __align__(16) float Ws[16][132];
    __shared__ __align__(16) float Xs[16][132];

    const int t  = threadIdx.x;
    const int tx = t & 15, ty = t >> 4;

    float acc[8][8];
#pragma unroll
    for (int i = 0; i < 8; ++i)
#pragma unroll
        for (int j = 0; j < 8; ++j) acc[i][j] = 0.f;

    for (int k0 = 0; k0 < K; k0 += 16) {
        {
            const int r  = t >> 2;
            const int c4 = (t & 3) * 4;
#pragma unroll
            for (int rr = 0; rr < 2; ++rr) {
                const int m = r + rr * 64;
                const float4 w4 = *(const float4*)(W + (size_t)(m0 + m) * K + k0 + c4);
                Ws[c4 + 0][m] = w4.x;
                Ws[c4 + 1][m] = w4.y;
                Ws[c4 + 2][m] = w4.z;
                Ws[c4 + 3][m] = w4.w;
            }
        }
        {
            const int kk = t >> 4;
            const int n4 = (t & 15) * 4;
#pragma unroll
            for (int cc = 0; cc < 2; ++cc) {
                const int n = n4 + cc * 64;
                *(float4*)&Xs[kk][n] = *(const float4*)(Xb + (size_t)(k0 + kk) * N + n0 + n);
            }
        }
        __syncthreads();

#pragma unroll
        for (int k = 0; k < 16; ++k) {
            float a[8], bb[8];
            *(float4*)&a[0]  = *(const float4*)&Ws[k][ty * 4];
            *(float4*)&a[4]  = *(const float4*)&Ws[k][64 + ty * 4];
            *(float4*)&bb[0] = *(const float4*)&Xs[k][tx * 4];
            *(float4*)&bb[4] = *(const float4*)&Xs[k][64 + tx * 4];
#pragma unroll
            for (int i = 0; i < 8; ++i)
#pragma unroll
                for (int j = 0; j < 8; ++j)
                    acc[i][j] += a[i] * bb[j];
        }
        __syncthreads();
    }

    float* Cb = C + (size_t)b * M * N;
#pragma unroll
    for (int i = 0; i < 8; ++i) {
        const int m = m0 + ((i < 4) ? (ty * 4 + i) : (64 + ty * 4 + (i - 4)));
#pragma unroll
        for (int jj = 0; jj < 2; ++jj) {
            const int n = n0 + jj * 64 + tx * 4;
            float4 v;
            v.x = acc[i][jj * 4 + 0];
            v.y = acc[i][jj * 4 + 1];
            v.z = acc[i][jj * 4 + 2];
            v.w = acc[i][jj * 4 + 3];
            const size_t off = (size_t)m * N + n;
            if (MODE == 0) {
                const float4 u4 = *(const float4*)(U + (size_t)b * M * N + off);
                v.x += u4.x; v.y += u4.y; v.z += u4.z; v.w += u4.w;
            } else if (MODE == 2) {
                const float bm = bias[m];
                const float4 r4 = *(const float4*)(res + (size_t)b * M * N + off);
                v.x += bm + r4.x; v.y += bm + r4.y; v.z += bm + r4.z; v.w += bm + r4.w;
            }
            *(float4*)(Cb + off) = v;
        }
    }
}

// ---------------------------------------------------------------------------
// MFMA bf16 fused rel-attention.
// Grid: (16 i-tiles, 16 heads, 4 batch), 256 threads = 4 waves.
// Wave w owns i-rows [w*16, w*16+16) of the 64-row i-tile.
// Per j-tile (64 keys):
//   AC   = (Q+rwb)^T K            : 4 N-tiles x K=64 -> 8 MFMA/wave
//   BDraw= (Q+rrb)^T RK (banded)  : 5 N-tiles (79-wide r window) -> 10 MFMA/wave
//   rel-shift gather BD[i][j] = BDraw[i][63-i_loc+j_loc] via fp32 LDS spill
//   online softmax in regs (16-lane shfl_xor reduces, 4 rows/lane)
//   PV: P(bf16 LDS) x V           : 4 N-tiles x K=64 -> 8 MFMA/wave
// ---------------------------------------------------------------------------
#define AT_PAD 72   // bf16 row stride: 144 B (16B-aligned, bank-rotating)

__global__ __launch_bounds__(256)
void attn_mfma_kernel(const float* __restrict__ wh,   // (B, 3072, 1024)
                      const float* __restrict__ rk,   // (1024, 1024)
                      const float* __restrict__ rwb,  // (16,64)
                      const float* __restrict__ rrb,  // (16,64)
                      float* __restrict__ av)         // (B, 1024, 1024)
{
    const int it = 15 - blockIdx.x;   // reversed: longest blocks first
    const int i0 = it * 64;
    const int n  = blockIdx.y;
    const int b  = blockIdx.z;

    const float* qg  = wh + ((size_t)b * 3072 + n * 64) * 1024;
    const float* kg  = qg + (size_t)1024 * 1024;
    const float* vg  = qg + (size_t)2048 * 1024;
    const float* rkg = rk + (size_t)(n * 64) * 1024;

    __shared__ __bf16 kt[64][AT_PAD];     // [j][d]   transposed K tile
    __shared__ __bf16 rkt[128][AT_PAD];   // [rr][d]  transposed RK window
    __shared__ __bf16 vs[64][AT_PAD];     // [d][j]   natural V tile
    __shared__ __bf16 ps[64][AT_PAD];     // [i][j]   probs (wave-private rows)
    __shared__ float  bd[64][132];        // [i][rr]  BDraw spill / output transpose

    const int t  = threadIdx.x;
    const int w  = t >> 6;
    const int l  = t & 63;
    const int lr = l & 15;
    const int lg = l >> 4;

    // ---- Q fragments (once per block): qa = q + rwb, qb = q + rrb ----
    bf16x8 qa[2], qb[2];
    {
        const int iq = i0 + w * 16 + lr;
#pragma unroll
        for (int h = 0; h < 2; ++h) {
            const int d0 = h * 32 + lg * 8;
#pragma unroll
            for (int e = 0; e < 8; ++e) {
                const float qv = qg[(size_t)(d0 + e) * 1024 + iq];
                qa[h][e] = f2bf(qv + rwb[n * 64 + d0 + e]);
                qb[h][e] = f2bf(qv + rrb[n * 64 + d0 + e]);
            }
        }
    }

    f32x4 acc_o[4];
#pragma unroll
    for (int i = 0; i < 4; ++i) acc_o[i] = (f32x4){0.f, 0.f, 0.f, 0.f};
    float m_r[4] = {-INFINITY, -INFINITY, -INFINITY, -INFINITY};
    float l_r[4] = {0.f, 0.f, 0.f, 0.f};

    const int njt = it + 1;
    const int rt0 = 3 - w;   // wave's first BD r-tile

    for (int jt = 0; jt < njt; ++jt) {
        const int j0 = jt * 64;
        __syncthreads();   // previous tile fully consumed

        // ---- stage kt (transposed), vs (natural) ----
        {
            const int d  = t >> 4;
            const int j4 = (t & 15) * 4;
#pragma unroll
            for (int k = 0; k < 4; ++k) {
                const int dd = d + k * 16;
                const float4 kv = *(const float4*)(kg + (size_t)dd * 1024 + j0 + j4);
                kt[j4 + 0][dd] = f2bf(kv.x);
                kt[j4 + 1][dd] = f2bf(kv.y);
                kt[j4 + 2][dd] = f2bf(kv.z);
                kt[j4 + 3][dd] = f2bf(kv.w);
                const float4 vv = *(const float4*)(vg + (size_t)dd * 1024 + j0 + j4);
                bf16x4 pk;
                pk[0] = f2bf(vv.x); pk[1] = f2bf(vv.y);
                pk[2] = f2bf(vv.z); pk[3] = f2bf(vv.w);
                *(bf16x4*)&vs[dd][j4] = pk;
            }
        }
        // ---- stage rkt (transposed, bounds: rbase >= 0 always, clamp top) ----
        const int rbase = j0 - i0 + 960;
        {
            const int d  = t >> 5;
            const int r4 = (t & 31) * 4;
#pragma unroll
            for (int k = 0; k < 8; ++k) {
                const int dd = d + k * 8;
                float4 rv;
                if (rbase + r4 < 1024)
                    rv = *(const float4*)(rkg + (size_t)dd * 1024 + rbase + r4);
                else
                    rv = make_float4(0.f, 0.f, 0.f, 0.f);
                rkt[r4 + 0][dd] = f2bf(rv.x);
                rkt[r4 + 1][dd] = f2bf(rv.y);
                rkt[r4 + 2][dd] = f2bf(rv.z);
                rkt[r4 + 3][dd] = f2bf(rv.w);
            }
        }
        __syncthreads();

        // ---- AC MFMAs ----
        f32x4 ac[4];
#pragma unroll
        for (int nt = 0; nt < 4; ++nt) {
            ac[nt] = (f32x4){0.f, 0.f, 0.f, 0.f};
#pragma unroll
            for (int h = 0; h < 2; ++h) {
                const bf16x8 bk = *(const bf16x8*)&kt[nt * 16 + lr][h * 32 + lg * 8];
                ac[nt] = MFMA16(qa[h], bk, ac[nt]);
            }
        }
        // ---- BDraw MFMAs (5 r-tiles covering this wave's window) ----
        f32x4 bda[5];
#pragma unroll
        for (int nt = 0; nt < 5; ++nt) {
            bda[nt] = (f32x4){0.f, 0.f, 0.f, 0.f};
#pragma unroll
            for (int h = 0; h < 2; ++h) {
                const bf16x8 br = *(const bf16x8*)&rkt[(rt0 + nt) * 16 + lr][h * 32 + lg * 8];
                bda[nt] = MFMA16(qb[h], br, bda[nt]);
            }
        }
        // spill BDraw (wave-private rows -> no barrier)
#pragma unroll
        for (int nt = 0; nt < 5; ++nt)
#pragma unroll
            for (int q = 0; q < 4; ++q)
                bd[w * 16 + lg * 4 + q][(rt0 + nt) * 16 + lr] = bda[nt][q];

        // ---- epilogue: gather BD, mask, online softmax ----
        float pm[4][4], tmax[4], tsum[4], cc[4];
#pragma unroll
        for (int q = 0; q < 4; ++q) {
            const int il = w * 16 + lg * 4 + q;
            const int gi = i0 + il;
            float mx = -INFINITY;
#pragma unroll
            for (int nt = 0; nt < 4; ++nt) {
                const int jl = nt * 16 + lr;
                const int gj = j0 + jl;
                float s = (ac[nt][q] + bd[il][63 - il + jl]) * 0.125f;
                const bool valid = (gj <= gi) && (gj >= gi - 999);
                s = valid ? s : -INFINITY;
                pm[q][nt] = s;
                mx = fmaxf(mx, s);
            }
            tmax[q] = mx;
        }
#pragma unroll
        for (int msk = 1; msk <= 8; msk <<= 1)
#pragma unroll
            for (int q = 0; q < 4; ++q)
                tmax[q] = fmaxf(tmax[q], __shfl_xor(tmax[q], msk));
#pragma unroll
        for (int q = 0; q < 4; ++q) {
            const float mnew = fmaxf(m_r[q], tmax[q]);
            cc[q] = __expf(m_r[q] - mnew);
            m_r[q] = mnew;
            float ts = 0.f;
#pragma unroll
            for (int nt = 0; nt < 4; ++nt) {
                const float p = __expf(pm[q][nt] - mnew);
                pm[q][nt] = p;
                ts += p;
            }
            tsum[q] = ts;
        }
#pragma unroll
        for (int msk = 1; msk <= 8; msk <<= 1)
#pragma unroll
            for (int q = 0; q < 4; ++q)
                tsum[q] += __shfl_xor(tsum[q], msk);
#pragma unroll
        for (int q = 0; q < 4; ++q)
            l_r[q] = l_r[q] * cc[q] + tsum[q];

        // write P (bf16, wave-private rows)
#pragma unroll
        for (int q = 0; q < 4; ++q)
#pragma unroll
            for (int nt = 0; nt < 4; ++nt)
                ps[w * 16 + lg * 4 + q][nt * 16 + lr] = f2bf(pm[q][nt]);

        // rescale O accumulators
#pragma unroll
        for (int ntd = 0; ntd < 4; ++ntd)
#pragma unroll
            for (int q = 0; q < 4; ++q)
                acc_o[ntd][q] *= cc[q];

        // ---- PV MFMAs ----
#pragma unroll
        for (int h = 0; h < 2; ++h) {
            const bf16x8 ap = *(const bf16x8*)&ps[w * 16 + lr][h * 32 + lg * 8];
#pragma unroll
            for (int ntd = 0; ntd < 4; ++ntd) {
                const bf16x8 bv = *(const bf16x8*)&vs[ntd * 16 + lr][h * 32 + lg * 8];
                acc_o[ntd] = MFMA16(ap, bv, acc_o[ntd]);
            }
        }
    }

    // ---- output: transpose through LDS (bd reuse), coalesced store ----
    float linv[4];
#pragma unroll
    for (int q = 0; q < 4; ++q) linv[q] = 1.f / l_r[q];

    __syncthreads();
#pragma unroll
    for (int hd = 0; hd < 2; ++hd) {
        if (hd) __syncthreads();
#pragma unroll
        for (int nn = 0; nn < 2; ++nn)
#pragma unroll
            for (int q = 0; q < 4; ++q)
                bd[nn * 16 + lr][w * 16 + lg * 4 + q] = acc_o[hd * 2 + nn][q] * linv[q];
        __syncthreads();
        const int dl = t >> 3;
        const int ic = (t & 7) * 8;
        float* dst = av + ((size_t)b * 1024 + n * 64 + hd * 32 + dl) * 1024 + i0 + ic;
        *(float4*)(dst + 0) = *(const float4*)&bd[dl][ic];
        *(float4*)(dst + 4) = *(const float4*)&bd[dl][ic + 4];
    }
}

// ---------------------------------------------------------------------------
// In-place channel LayerNorm over dim 1 of (B, 1024, 1024).
// ---------------------------------------------------------------------------
__global__ __launch_bounds__(256)
void ln_kernel(float* __restrict__ x)
{
    const int b  = blockIdx.y;
    const int li = threadIdx.x & 63;
    const int cp = threadIdx.x >> 6;
    const int l  = blockIdx.x * 64 + li;
    float* xb = x + (size_t)b * D_MODEL * QLEN;

    float s = 0.f, s2 = 0.f;
    for (int c = cp * 256; c < (cp + 1) * 256; ++c) {
        const float v = xb[(size_t)c * QLEN + l];
        s += v; s2 += v * v;
    }
    __shared__ float sum1[4][64], sum2[4][64], mean[64], rstd[64];
    sum1[cp][li] = s;
    sum2[cp][li] = s2;
    __syncthreads();
    if (threadIdx.x < 64) {
        const int q = threadIdx.x;
        const float a  = sum1[0][q] + sum1[1][q] + sum1[2][q] + sum1[3][q];
        const float a2 = sum2[0][q] + sum2[1][q] + sum2[2][q] + sum2[3][q];
        const float mu  = a * (1.f / 1024.f);
        const float var = a2 * (1.f / 1024.f) - mu * mu;
        mean[q] = mu;
        rstd[q] = rsqrtf(var + 1e-5f);
    }
    __syncthreads();
    const float mu = mean[li];
    const float rs = rstd[li];
    for (int c = cp * 256; c < (cp + 1) * 256; ++c) {
        const size_t idx = (size_t)c * QLEN + l;
        xb[idx] = (xb[idx] - mu) * rs;
    }
}

// ---------------------------------------------------------------------------
extern "C" void kernel_launch(void* const* d_in, const int* in_sizes, int n_in,
                              void* d_out, int out_size, void* d_ws, size_t ws_size,
                              hipStream_t stream)
{
    const float* z     = (const float*)d_in[0];
    const float* pos   = (const float*)d_in[1];
    const float* u     = (const float*)d_in[2];
    const float* qkv_w = (const float*)d_in[3];
    const float* r_w   = (const float*)d_in[4];
    const float* rwb   = (const float*)d_in[5];
    const float* rrb   = (const float*)d_in[6];
    const float* o_w   = (const float*)d_in[7];
    const float* o_b   = (const float*)d_in[8];
    float* out = (float*)d_out;

    float* wh  = (float*)d_ws;                   // 4*3072*1024
    float* rkw = wh + (size_t)4 * 3072 * 1024;   // 1024*1024
    float* avb = rkw + (size_t)1024 * 1024;      // 4*1024*1024

    gemm_kernel<0><<<dim3(8, 24, 4), 256, 0, stream>>>(
        qkv_w, z, u, nullptr, nullptr, wh, 3072, 1024, 1024);

    gemm_kernel<1><<<dim3(8, 8, 1), 256, 0, stream>>>(
        r_w, pos, nullptr, nullptr, nullptr, rkw, 1024, 1024, 1024);

    attn_mfma_kernel<<<dim3(16, 16, 4), 256, 0, stream>>>(wh, rkw, rwb, rrb, avb);

    gemm_kernel<2><<<dim3(8, 8, 4), 256, 0, stream>>>(
        o_w, avb, nullptr, o_b, z, out, 1024, 1024, 1024);

    ln_kernel<<<dim3(16, 4), 256, 0, stream>>>(out);
}

// Round 3
// 286.711 us; speedup vs baseline: 7.5931x; 3.0367x over previous
//
#include <hip/hip_runtime.h>
#include <cmath>

#define D_MODEL 1024
#define QLEN    1024
#define NHEAD   16
#define DHEAD   64
#define BSZ     4

typedef __bf16 bf16x8 __attribute__((ext_vector_type(8)));
typedef __bf16 bf16x4 __attribute__((ext_vector_type(4)));
typedef float  f32x4  __attribute__((ext_vector_type(4)));

static __device__ __forceinline__ __bf16 f2bf(float x) { return (__bf16)x; }

#define MFMA16(a, b, c) __builtin_amdgcn_mfma_f32_16x16x32_bf16((a), (b), (c), 0, 0, 0)

// ---------------------------------------------------------------------------
// fp32 -> bf16 flat convert (weights). n8 = elements/8.
// ---------------------------------------------------------------------------
__global__ __launch_bounds__(256)
void cvt_kernel(const float* __restrict__ s, __bf16* __restrict__ d, int n8)
{
    const int i = blockIdx.x * 256 + threadIdx.x;
    if (i >= n8) return;
    const float4 a = *(const float4*)(s + (size_t)i * 8);
    const float4 b = *(const float4*)(s + (size_t)i * 8 + 4);
    bf16x8 o;
    o[0] = f2bf(a.x); o[1] = f2bf(a.y); o[2] = f2bf(a.z); o[3] = f2bf(a.w);
    o[4] = f2bf(b.x); o[5] = f2bf(b.y); o[6] = f2bf(b.z); o[7] = f2bf(b.w);
    *(bf16x8*)(d + (size_t)i * 8) = o;
}

// ---------------------------------------------------------------------------
// Transpose + convert: src fp32 [1024 c][1024 l] -> dst bf16 [1024 l][1024 c].
// Slabs 0-3: z batches; slab 4: pos_emb.
// ---------------------------------------------------------------------------
__global__ __launch_bounds__(256)
void transpose_cvt_kernel(const float* __restrict__ z, const float* __restrict__ pos,
                          __bf16* __restrict__ zT, __bf16* __restrict__ posT)
{
    const int slab = blockIdx.z;
    const float* src = (slab < 4) ? z + (size_t)slab * 1048576 : pos;
    __bf16*      dst = (slab < 4) ? zT + (size_t)slab * 1048576 : posT;
    const int c0 = blockIdx.y * 64, l0 = blockIdx.x * 64;

    __shared__ float tile[64][68];
    const int t = threadIdx.x;
    {
        const int c = t >> 4, l4 = (t & 15) * 4;
#pragma unroll
        for (int r = 0; r < 4; ++r) {
            const int cc = c + r * 16;
            const float4 v = *(const float4*)(src + (size_t)(c0 + cc) * 1024 + l0 + l4);
            tile[cc][l4 + 0] = v.x; tile[cc][l4 + 1] = v.y;
            tile[cc][l4 + 2] = v.z; tile[cc][l4 + 3] = v.w;
        }
    }
    __syncthreads();
    {
        const int l = t >> 2, cb = (t & 3) * 16;
#pragma unroll
        for (int h = 0; h < 2; ++h) {
            bf16x8 o;
#pragma unroll
            for (int e = 0; e < 8; ++e) o[e] = f2bf(tile[cb + h * 8 + e][l]);
            *(bf16x8*)(dst + (size_t)(l0 + l) * 1024 + c0 + cb + h * 8) = o;
        }
    }
}

// ---------------------------------------------------------------------------
// bf16 MFMA GEMM: C[b][m][n] = sum_k A[m][k] * B[b][n][k]^T + epilogue
//   A: [M][K] bf16 (weights);  Bm: [b][N][K] bf16 (pre-transposed activations)
//   MODE 0: + add32[b][m][n] -> bf16 C       (QKV: +u -> wh)
//   MODE 1: -> bf16 C                        (r_head_k)
//   MODE 2: + bias[m] + add32[b][m][n] -> fp32 C  (out proj + o_b + z)
// 128x128 tile, BK=64, 4 waves (2x2), 4x4 16x16x32 frags per wave.
// ---------------------------------------------------------------------------
template<int MODE>
__global__ __launch_bounds__(256)
void bgemm_kernel(const __bf16* __restrict__ A, const __bf16* __restrict__ Bm,
                  const float* __restrict__ add32, const float* __restrict__ bias,
                  void* __restrict__ Cout, int M, int K, int N)
{
    const int b  = blockIdx.z;
    const int m0 = blockIdx.y * 128;
    const int n0 = blockIdx.x * 128;
    const __bf16* Bb = Bm + (size_t)b * N * K;

    __shared__ __bf16 As[128][72];
    __shared__ __bf16 Bs[128][72];

    const int t  = threadIdx.x;
    const int w  = t >> 6, l = t & 63;
    const int lr = l & 15, lg = l >> 4;
    const int wr = w >> 1, wc = w & 1;

    f32x4 acc[4][4];
#pragma unroll
    for (int mi = 0; mi < 4; ++mi)
#pragma unroll
        for (int ni = 0; ni < 4; ++ni) acc[mi][ni] = (f32x4){0.f, 0.f, 0.f, 0.f};

    const int srow = t >> 1, sh = (t & 1) * 32;

    for (int k0 = 0; k0 < K; k0 += 64) {
        __syncthreads();
        const __bf16* ag = A  + (size_t)(m0 + srow) * K + k0 + sh;
        const __bf16* bg = Bb + (size_t)(n0 + srow) * K + k0 + sh;
#pragma unroll
        for (int j = 0; j < 4; ++j) {
            *(bf16x8*)&As[srow][sh + j * 8] = *(const bf16x8*)(ag + j * 8);
            *(bf16x8*)&Bs[srow][sh + j * 8] = *(const bf16x8*)(bg + j * 8);
        }
        __syncthreads();

#pragma unroll
        for (int kk = 0; kk < 2; ++kk) {
            bf16x8 af[4], bfr[4];
#pragma unroll
            for (int mi = 0; mi < 4; ++mi)
                af[mi] = *(const bf16x8*)&As[wr * 64 + mi * 16 + lr][kk * 32 + lg * 8];
#pragma unroll
            for (int ni = 0; ni < 4; ++ni)
                bfr[ni] = *(const bf16x8*)&Bs[wc * 64 + ni * 16 + lr][kk * 32 + lg * 8];
#pragma unroll
            for (int mi = 0; mi < 4; ++mi)
#pragma unroll
                for (int ni = 0; ni < 4; ++ni)
                    acc[mi][ni] = MFMA16(af[mi], bfr[ni], acc[mi][ni]);
        }
    }

    const size_t cb = (size_t)b * M * N;
#pragma unroll
    for (int mi = 0; mi < 4; ++mi)
#pragma unroll
    for (int q = 0; q < 4; ++q) {
        const int m = m0 + wr * 64 + mi * 16 + lg * 4 + q;
#pragma unroll
        for (int ni = 0; ni < 4; ++ni) {
            const int n = n0 + wc * 64 + ni * 16 + lr;
            float v = acc[mi][ni][q];
            const size_t off = cb + (size_t)m * N + n;
            if (MODE == 0) {
                v += add32[off];
                ((__bf16*)Cout)[off] = f2bf(v);
            } else if (MODE == 1) {
                ((__bf16*)Cout)[off] = f2bf(v);
            } else {
                v += bias[m] + add32[off];
                ((float*)Cout)[off] = v;
            }
        }
    }
}

// ---------------------------------------------------------------------------
// MFMA bf16 fused rel-attention (bf16 wh/rk in, bf16 avT out).
// Grid: (16 i-tiles, 16 heads, 4 batch), 256 threads = 4 waves.
// avT layout: [b][l][n*64+d]  (== B-operand layout for the out-projection GEMM)
// ---------------------------------------------------------------------------
#define AT_PAD 72

__global__ __launch_bounds__(256)
void attn_mfma_kernel(const __bf16* __restrict__ wh,   // (B, 3072, 1024)
                      const __bf16* __restrict__ rk,   // (1024, 1024)
                      const float* __restrict__ rwb,   // (16,64)
                      const float* __restrict__ rrb,   // (16,64)
                      __bf16* __restrict__ avT)        // (B, 1024, 1024) [l][c]
{
    const int it = 15 - blockIdx.x;
    const int i0 = it * 64;
    const int n  = blockIdx.y;
    const int b  = blockIdx.z;

    const __bf16* qg  = wh + ((size_t)b * 3072 + n * 64) * 1024;
    const __bf16* kg  = qg + (size_t)1024 * 1024;
    const __bf16* vg  = qg + (size_t)2048 * 1024;
    const __bf16* rkg = rk + (size_t)(n * 64) * 1024;

    __shared__ __bf16 kt[64][AT_PAD];     // [j][d]
    __shared__ __bf16 rkt[128][AT_PAD];   // [rr][d]
    __shared__ __bf16 vs[64][AT_PAD];     // [d][j]
    __shared__ __bf16 ps[64][AT_PAD];     // [i][j] probs / final [i][d] out
    __shared__ float  bd[64][132];        // [i][rr] BDraw spill

    const int t  = threadIdx.x;
    const int w  = t >> 6;
    const int l  = t & 63;
    const int lr = l & 15;
    const int lg = l >> 4;

    // staging lane mapping: sd = d-row, chunk along j/r
    const int sd  = t & 63;
    const int sjc = (t >> 6) * 16;
    const int src_ = (t >> 6) * 32;

    // ---- Q fragments: qa = q + rwb, qb = q + rrb ----
    bf16x8 qa[2], qb[2];
    {
        const int iq = i0 + w * 16 + lr;
#pragma unroll
        for (int h = 0; h < 2; ++h) {
            const int d0 = h * 32 + lg * 8;
#pragma unroll
            for (int e = 0; e < 8; ++e) {
                const float qv = (float)qg[(size_t)(d0 + e) * 1024 + iq];
                qa[h][e] = f2bf(qv + rwb[n * 64 + d0 + e]);
                qb[h][e] = f2bf(qv + rrb[n * 64 + d0 + e]);
            }
        }
    }

    f32x4 acc_o[4];
#pragma unroll
    for (int i = 0; i < 4; ++i) acc_o[i] = (f32x4){0.f, 0.f, 0.f, 0.f};
    float m_r[4] = {-INFINITY, -INFINITY, -INFINITY, -INFINITY};
    float l_r[4] = {0.f, 0.f, 0.f, 0.f};

    const int njt = it + 1;
    const int rt0 = 3 - w;

    for (int jt = 0; jt < njt; ++jt) {
        const int j0 = jt * 64;
        __syncthreads();

        // ---- stage kt (transposed), vs (natural) ----
#pragma unroll
        for (int u2 = 0; u2 < 2; ++u2) {
            const int jj = sjc + u2 * 8;
            const bf16x8 kv8 = *(const bf16x8*)(kg + (size_t)sd * 1024 + j0 + jj);
#pragma unroll
            for (int e = 0; e < 8; ++e) kt[jj + e][sd] = kv8[e];
            const bf16x8 vv8 = *(const bf16x8*)(vg + (size_t)sd * 1024 + j0 + jj);
            *(bf16x8*)&vs[sd][jj] = vv8;
        }
        // ---- stage rkt (transposed, clamp top) ----
        const int rbase = j0 - i0 + 960;
#pragma unroll
        for (int u4 = 0; u4 < 4; ++u4) {
            const int rr = src_ + u4 * 8;
            bf16x8 rv8;
            if (rbase + rr < 1024)
                rv8 = *(const bf16x8*)(rkg + (size_t)sd * 1024 + rbase + rr);
            else {
#pragma unroll
                for (int e = 0; e < 8; ++e) rv8[e] = f2bf(0.f);
            }
#pragma unroll
            for (int e = 0; e < 8; ++e) rkt[rr + e][sd] = rv8[e];
        }
        __syncthreads();

        // ---- AC MFMAs ----
        f32x4 ac[4];
#pragma unroll
        for (int nt = 0; nt < 4; ++nt) {
            ac[nt] = (f32x4){0.f, 0.f, 0.f, 0.f};
#pragma unroll
            for (int h = 0; h < 2; ++h) {
                const bf16x8 bk = *(const bf16x8*)&kt[nt * 16 + lr][h * 32 + lg * 8];
                ac[nt] = MFMA16(qa[h], bk, ac[nt]);
            }
        }
        // ---- BDraw MFMAs ----
        f32x4 bda[5];
#pragma unroll
        for (int nt = 0; nt < 5; ++nt) {
            bda[nt] = (f32x4){0.f, 0.f, 0.f, 0.f};
#pragma unroll
            for (int h = 0; h < 2; ++h) {
                const bf16x8 br = *(const bf16x8*)&rkt[(rt0 + nt) * 16 + lr][h * 32 + lg * 8];
                bda[nt] = MFMA16(qb[h], br, bda[nt]);
            }
        }
#pragma unroll
        for (int nt = 0; nt < 5; ++nt)
#pragma unroll
            for (int q = 0; q < 4; ++q)
                bd[w * 16 + lg * 4 + q][(rt0 + nt) * 16 + lr] = bda[nt][q];

        // ---- epilogue: gather BD, mask, online softmax ----
        float pm[4][4], tmax[4], tsum[4], cc[4];
#pragma unroll
        for (int q = 0; q < 4; ++q) {
            const int il = w * 16 + lg * 4 + q;
            const int gi = i0 + il;
            float mx = -INFINITY;
#pragma unroll
            for (int nt = 0; nt < 4; ++nt) {
                const int jl = nt * 16 + lr;
                const int gj = j0 + jl;
                float s = (ac[nt][q] + bd[il][63 - il + jl]) * 0.125f;
                const bool valid = (gj <= gi) && (gj >= gi - 999);
                s = valid ? s : -INFINITY;
                pm[q][nt] = s;
                mx = fmaxf(mx, s);
            }
            tmax[q] = mx;
        }
#pragma unroll
        for (int msk = 1; msk <= 8; msk <<= 1)
#pragma unroll
            for (int q = 0; q < 4; ++q)
                tmax[q] = fmaxf(tmax[q], __shfl_xor(tmax[q], msk));
#pragma unroll
        for (int q = 0; q < 4; ++q) {
            const float mnew = fmaxf(m_r[q], tmax[q]);
            cc[q] = __expf(m_r[q] - mnew);
            m_r[q] = mnew;
            float ts = 0.f;
#pragma unroll
            for (int nt = 0; nt < 4; ++nt) {
                const float p = __expf(pm[q][nt] - mnew);
                pm[q][nt] = p;
                ts += p;
            }
            tsum[q] = ts;
        }
#pragma unroll
        for (int msk = 1; msk <= 8; msk <<= 1)
#pragma unroll
            for (int q = 0; q < 4; ++q)
                tsum[q] += __shfl_xor(tsum[q], msk);
#pragma unroll
        for (int q = 0; q < 4; ++q)
            l_r[q] = l_r[q] * cc[q] + tsum[q];

#pragma unroll
        for (int q = 0; q < 4; ++q)
#pragma unroll
            for (int nt = 0; nt < 4; ++nt)
                ps[w * 16 + lg * 4 + q][nt * 16 + lr] = f2bf(pm[q][nt]);

#pragma unroll
        for (int ntd = 0; ntd < 4; ++ntd)
#pragma unroll
            for (int q = 0; q < 4; ++q)
                acc_o[ntd][q] *= cc[q];

        // ---- PV MFMAs ----
#pragma unroll
        for (int h = 0; h < 2; ++h) {
            const bf16x8 ap = *(const bf16x8*)&ps[w * 16 + lr][h * 32 + lg * 8];
#pragma unroll
            for (int ntd = 0; ntd < 4; ++ntd) {
                const bf16x8 bv = *(const bf16x8*)&vs[ntd * 16 + lr][h * 32 + lg * 8];
                acc_o[ntd] = MFMA16(ap, bv, acc_o[ntd]);
            }
        }
    }

    // ---- output: [i][d] bf16 via ps reuse, coalesced avT store ----
    float linv[4];
#pragma unroll
    for (int q = 0; q < 4; ++q) linv[q] = 1.f / l_r[q];

    __syncthreads();
#pragma unroll
    for (int ntd = 0; ntd < 4; ++ntd)
#pragma unroll
        for (int q = 0; q < 4; ++q)
            ps[w * 16 + lg * 4 + q][ntd * 16 + lr] = f2bf(acc_o[ntd][q] * linv[q]);
    __syncthreads();
    {
        const int oi = t >> 2, odc = (t & 3) * 16;
        __bf16* dst = avT + ((size_t)b * 1024 + i0 + oi) * 1024 + n * 64 + odc;
        *(bf16x8*)(dst + 0) = *(const bf16x8*)&ps[oi][odc];
        *(bf16x8*)(dst + 8) = *(const bf16x8*)&ps[oi][odc + 8];
    }
}

// ---------------------------------------------------------------------------
// In-place channel LayerNorm over dim 1 of (B, 1024, 1024).
// ---------------------------------------------------------------------------
__global__ __launch_bounds__(256)
void ln_kernel(float* __restrict__ x)
{
    const int b  = blockIdx.y;
    const int li = threadIdx.x & 63;
    const int cp = threadIdx.x >> 6;
    const int l  = blockIdx.x * 64 + li;
    float* xb = x + (size_t)b * D_MODEL * QLEN;

    float s = 0.f, s2 = 0.f;
    for (int c = cp * 256; c < (cp + 1) * 256; ++c) {
        const float v = xb[(size_t)c * QLEN + l];
        s += v; s2 += v * v;
    }
    __shared__ float sum1[4][64], sum2[4][64], mean[64], rstd[64];
    sum1[cp][li] = s;
    sum2[cp][li] = s2;
    __syncthreads();
    if (threadIdx.x < 64) {
        const int q = threadIdx.x;
        const float a  = sum1[0][q] + sum1[1][q] + sum1[2][q] + sum1[3][q];
        const float a2 = sum2[0][q] + sum2[1][q] + sum2[2][q] + sum2[3][q];
        const float mu  = a * (1.f / 1024.f);
        const float var = a2 * (1.f / 1024.f) - mu * mu;
        mean[q] = mu;
        rstd[q] = rsqrtf(var + 1e-5f);
    }
    __syncthreads();
    const float mu = mean[li];
    const float rs = rstd[li];
    for (int c = cp * 256; c < (cp + 1) * 256; ++c) {
        const size_t idx = (size_t)c * QLEN + l;
        xb[idx] = (xb[idx] - mu) * rs;
    }
}

// ---------------------------------------------------------------------------
extern "C" void kernel_launch(void* const* d_in, const int* in_sizes, int n_in,
                              void* d_out, int out_size, void* d_ws, size_t ws_size,
                              hipStream_t stream)
{
    const float* z     = (const float*)d_in[0];
    const float* pos   = (const float*)d_in[1];
    const float* u     = (const float*)d_in[2];
    const float* qkv_w = (const float*)d_in[3];
    const float* r_w   = (const float*)d_in[4];
    const float* rwb   = (const float*)d_in[5];
    const float* rrb   = (const float*)d_in[6];
    const float* o_w   = (const float*)d_in[7];
    const float* o_b   = (const float*)d_in[8];
    float* out = (float*)d_out;

    char* p = (char*)d_ws;
    __bf16* wh_bf  = (__bf16*)p;  p += (size_t)4 * 3072 * 1024 * 2;   // 25.2 MB
    __bf16* rkw_bf = (__bf16*)p;  p += (size_t)1024 * 1024 * 2;       //  2.1 MB
    __bf16* avT    = (__bf16*)p;  p += (size_t)4 * 1024 * 1024 * 2;   //  8.4 MB
    __bf16* zT     = (__bf16*)p;  p += (size_t)4 * 1024 * 1024 * 2;   //  8.4 MB
    __bf16* posT   = (__bf16*)p;  p += (size_t)1024 * 1024 * 2;       //  2.1 MB
    __bf16* qw_bf  = (__bf16*)p;  p += (size_t)3072 * 1024 * 2;       //  6.3 MB
    __bf16* rw_bf  = (__bf16*)p;  p += (size_t)1024 * 1024 * 2;       //  2.1 MB
    __bf16* ow_bf  = (__bf16*)p;                                      //  2.1 MB

    // prep: weight converts + activation transposes
    cvt_kernel<<<1536, 256, 0, stream>>>(qkv_w, qw_bf, 3072 * 1024 / 8);
    cvt_kernel<<<512,  256, 0, stream>>>(r_w,   rw_bf, 1024 * 1024 / 8);
    cvt_kernel<<<512,  256, 0, stream>>>(o_w,   ow_bf, 1024 * 1024 / 8);
    transpose_cvt_kernel<<<dim3(16, 16, 5), 256, 0, stream>>>(z, pos, zT, posT);

    // 1. wh = qkv_w @ z + u   (bf16 out)
    bgemm_kernel<0><<<dim3(8, 24, 4), 256, 0, stream>>>(
        qw_bf, zT, u, nullptr, wh_bf, 3072, 1024, 1024);

    // 2. rk = r_w @ pos       (bf16 out)
    bgemm_kernel<1><<<dim3(8, 8, 1), 256, 0, stream>>>(
        rw_bf, posT, nullptr, nullptr, rkw_bf, 1024, 1024, 1024);

    // 3. fused rel-attention -> avT (bf16, [b][l][c])
    attn_mfma_kernel<<<dim3(16, 16, 4), 256, 0, stream>>>(wh_bf, rkw_bf, rwb, rrb, avT);

    // 4. out = o_w @ attn_vec + o_b + z  (fp32, into d_out)
    bgemm_kernel<2><<<dim3(8, 8, 4), 256, 0, stream>>>(
        ow_bf, avT, z, o_b, out, 1024, 1024, 1024);

    // 5. channel LayerNorm in place
    ln_kernel<<<dim3(16, 4), 256, 0, stream>>>(out);
}